// Round 3
// baseline (69.810 us; speedup 1.0000x reference)
//
#include <hip/hip_runtime.h>

#define BDIM 8192
#define DDIM 256
#define NSLOTS 512

typedef __bf16 bf16x8 __attribute__((ext_vector_type(8)));
typedef float f32x4 __attribute__((ext_vector_type(4)));
typedef unsigned short u16x4 __attribute__((ext_vector_type(4)));

#define MEMF() asm volatile("" ::: "memory")
#define BARR()                       \
  do {                               \
    MEMF();                          \
    __builtin_amdgcn_s_barrier();    \
    MEMF();                          \
  } while (0)
#define VMW(n) asm volatile("s_waitcnt vmcnt(" #n ")" ::: "memory")

__device__ inline unsigned short f2bf(float f) {
  unsigned u = __float_as_uint(f);
  u += 0x7FFFu + ((u >> 16) & 1u);  // round-to-nearest-even
  return (unsigned short)(u >> 16);
}
__device__ inline float bf2f(unsigned short h) {
  return __uint_as_float(((unsigned)h) << 16);
}

// Direct global->LDS DMA, 16B/lane. LDS operand = wave-uniform base; HW
// scatters lane*16. Global source is per-lane (carries the swizzle).
__device__ inline void gload_lds16(const void* g, void* l) {
  __builtin_amdgcn_global_load_lds(
      (const __attribute__((address_space(1))) void*)g,
      (__attribute__((address_space(3))) void*)l, 16, 0, 0);
}

// ---------------------------------------------------------------------------
// Kernel 1: normalize rows and convert to bf16, once. One wave per row.
// ---------------------------------------------------------------------------
__global__ __launch_bounds__(256) void norm_convert_kernel(
    const float* __restrict__ t, const float* __restrict__ v,
    unsigned short* __restrict__ tn, unsigned short* __restrict__ vn) {
  int wid = threadIdx.x >> 6, lane = threadIdx.x & 63;
  int row = blockIdx.x * 4 + wid;
  const float* src;
  unsigned short* dst;
  if (row < BDIM) {
    src = t + (size_t)row * DDIM;
    dst = tn + (size_t)row * DDIM;
  } else {
    int r = row - BDIM;
    src = v + (size_t)r * DDIM;
    dst = vn + (size_t)r * DDIM;
  }
  float4 x = reinterpret_cast<const float4*>(src)[lane];
  float ss = x.x * x.x + x.y * x.y + x.z * x.z + x.w * x.w;
  #pragma unroll
  for (int off = 1; off < 64; off <<= 1) ss += __shfl_xor(ss, off, 64);
  float sc = 1.0f / fmaxf(sqrtf(ss), 1e-12f);
  u16x4 w;
  w[0] = f2bf(x.x * sc); w[1] = f2bf(x.y * sc);
  w[2] = f2bf(x.z * sc); w[3] = f2bf(x.w * sc);
  reinterpret_cast<u16x4*>(dst)[lane] = w;
}

// ---------------------------------------------------------------------------
// Kernel 2: 256x256-tile bf16 GEMM, 8 waves (2Mx4N), BK=64, 8-phase-style
// schedule: 4 phases per K-tile (one C-quadrant = 16 MFMA each), staging
// spread 2 gload_lds/phase into the opposite (fully dead) buffer, COUNTED
// vmcnt (never 0 in steady state), setprio around each MFMA cluster.
//
// Region->phase deadness (m-major quadrants: mh=q>>1, nh=q&1):
//   A rows [wm*128+mh*64, +64) read only in phases of that mh.
//   B quarter [wn*64, +64): low half read P1,P3; high half P2,P4
//     -> ALL of B must be resident before P1; A-odd halves before P3.
// Stage order during tile t (for t+1): P1:B0,B1  P2:B2,B3  P3:A0,A2  P4:A1,A3
// Waits: vmcnt(4) @P2 (covers A1,A3 of tile t, issued P4 of t-1);
//        vmcnt(2) @P4 (covers all of t+1 except A1,A3, the 2 newest loads).
//
// LDS swizzle (involution, both sides): granule' = granule ^ (row&7);
// applied on the per-lane GLOBAL source (DMA dest stays linear) and on the
// ds_read address. 8-lane groups of a ds_read_b128 then cover all 32 banks.
// ---------------------------------------------------------------------------
__global__ __launch_bounds__(512) void loss_kernel(
    const unsigned short* __restrict__ tn,
    const unsigned short* __restrict__ vn, float* __restrict__ slots) {
  __shared__ unsigned short Asb[2][16384];  // [buf][256 rows][64 cols]
  __shared__ unsigned short Bsb[2][16384];
  __shared__ float rbuf[8];

  const int tid = threadIdx.x;
  const int lane = tid & 63;
  const int wid = tid >> 6;
  const int l15 = lane & 15;
  const int l4 = lane >> 4;
  const int wm = wid >> 2;  // 0..1: wave's 128-row half
  const int wn = wid & 3;   // 0..3: wave's 64-col quarter

  // XCD-aware bijective swizzle: 1024 blocks, 8 XCDs, 128 blocks/XCD.
  const int flat = blockIdx.x;
  const int nb = (flat & 7) * 128 + (flat >> 3);
  const int rowBase = (nb >> 5) * 256;
  const int colBase = (nb & 31) * 256;

  // Staging: one round = 64 rows (512 threads x 16B = 8KB).
  // thread -> row (tid>>3) within region, granule (tid&7); source granule
  // pre-swizzled so linear DMA dest yields swizzled LDS content.
  const int sg = (tid & 7) ^ ((tid >> 3) & 7);
  const unsigned short* gAsrc =
      tn + (size_t)(rowBase + (tid >> 3)) * DDIM + sg * 8;
  const unsigned short* gBsrc =
      vn + (size_t)(colBase + (tid >> 3)) * DDIM + sg * 8;
  const int ldsStage = wid * 512;  // shorts; wave-uniform base

  auto stA = [&](int ob, int rg, int kt) {
    gload_lds16(gAsrc + (size_t)rg * 64 * DDIM + kt * 64,
                &Asb[ob][rg * 4096 + ldsStage]);
  };
  auto stB = [&](int ob, int rg, int kt) {
    gload_lds16(gBsrc + (size_t)rg * 64 * DDIM + kt * 64,
                &Bsb[ob][rg * 4096 + ldsStage]);
  };

  // Prologue: tile 0 into buf0, A1/A3 last; keep them in flight (vmcnt(2)).
  stB(0, 0, 0); stB(0, 1, 0); stB(0, 2, 0); stB(0, 3, 0);
  stA(0, 0, 0); stA(0, 2, 0);
  stA(0, 1, 0); stA(0, 3, 0);
  VMW(2);
  BARR();

  f32x4 acc[8][4];
  #pragma unroll
  for (int i = 0; i < 8; ++i)
    #pragma unroll
    for (int j = 0; j < 4; ++j) acc[i][j] = (f32x4)(0.0f);

  #pragma unroll
  for (int t = 0; t < 4; ++t) {  // K-tiles (K=256, BK=64)
    const int cur = t & 1, ob = cur ^ 1, kt = t + 1;
    #pragma unroll
    for (int q = 0; q < 4; ++q) {  // phases = C-quadrants
      const int mh = q >> 1, nh = q & 1;
      // 12 ds_read_b128: 8 A-frags + 4 B-frags for this quadrant.
      bf16x8 af[4][2], bv[2][2];
      #pragma unroll
      for (int mm = 0; mm < 4; ++mm) {
        const int row = wm * 128 + (mh * 4 + mm) * 16 + l15;  // row&7==l15&7
        #pragma unroll
        for (int kk = 0; kk < 2; ++kk) {
          const int gg = (kk * 4 + l4) ^ (l15 & 7);
          af[mm][kk] =
              *reinterpret_cast<const bf16x8*>(&Asb[cur][row * 64 + gg * 8]);
        }
      }
      #pragma unroll
      for (int nn = 0; nn < 2; ++nn) {
        const int row = wn * 64 + (nh * 2 + nn) * 16 + l15;
        #pragma unroll
        for (int kk = 0; kk < 2; ++kk) {
          const int gg = (kk * 4 + l4) ^ (l15 & 7);
          bv[nn][kk] =
              *reinterpret_cast<const bf16x8*>(&Bsb[cur][row * 64 + gg * 8]);
        }
      }
      // Prefetch tile t+1 into the opposite buffer (dead since end of t-1).
      if (t < 3) {
        if (q == 0)      { stB(ob, 0, kt); stB(ob, 1, kt); }
        else if (q == 1) { stB(ob, 2, kt); stB(ob, 3, kt); }
        else if (q == 2) { stA(ob, 0, kt); stA(ob, 2, kt); }
        else             { stA(ob, 1, kt); stA(ob, 3, kt); }
      }
      // Counted waits (per-wave flight accounting; see header comment).
      if (q == 1) {
        if (t < 3) VMW(4); else VMW(0);
      }
      if (q == 3 && t < 3) VMW(2);
      BARR();
      asm volatile("s_waitcnt lgkmcnt(0)" ::: "memory");
      __builtin_amdgcn_s_setprio(1);
      #pragma unroll
      for (int mm = 0; mm < 4; ++mm)
        #pragma unroll
        for (int nn = 0; nn < 2; ++nn)
          #pragma unroll
          for (int kk = 0; kk < 2; ++kk)
            acc[mh * 4 + mm][nh * 2 + nn] =
                __builtin_amdgcn_mfma_f32_16x16x32_bf16(
                    af[mm][kk], bv[nn][kk], acc[mh * 4 + mm][nh * 2 + nn], 0,
                    0, 0);
      __builtin_amdgcn_s_setprio(0);
      BARR();
    }
  }

  // Position-blind epilogue: 0.7*max(s,0)^2 for every element.
  float lsum = 0.0f;
  #pragma unroll
  for (int m = 0; m < 8; ++m)
    #pragma unroll
    for (int n = 0; n < 4; ++n)
      #pragma unroll
      for (int r = 0; r < 4; ++r) {
        float u = fmaxf(acc[m][n][r], 0.0f);
        lsum = fmaf(u, u, lsum);
      }
  lsum *= 0.7f;  // LAMBDA_NEG
  #pragma unroll
  for (int off = 1; off < 64; off <<= 1) lsum += __shfl_xor(lsum, off, 64);
  if (lane == 0) rbuf[wid] = lsum;
  __syncthreads();
  if (tid == 0) {
    float s = 0.0f;
    #pragma unroll
    for (int w = 0; w < 8; ++w) s += rbuf[w];
    atomicAdd(&slots[flat & (NSLOTS - 1)], s);
  }
}

// ---------------------------------------------------------------------------
// Kernel 3: sparse fixups, one wave per row. Diagonal: replace
// 0.7*max(s,0)^2 with (s-1)^2; each dedup'd valid semi j: replace with
// 0.7*max(0.7-s,0)^2. Same bf16 inputs + fp32 accum as the MFMA path.
// ---------------------------------------------------------------------------
__global__ __launch_bounds__(256) void corr_kernel(
    const unsigned short* __restrict__ tn,
    const unsigned short* __restrict__ vn, const int* __restrict__ sidx,
    float* __restrict__ slots) {
  int wid = threadIdx.x >> 6, lane = threadIdx.x & 63;
  int i = blockIdx.x * 4 + wid;

  u16x4 ta = reinterpret_cast<const u16x4*>(tn + (size_t)i * DDIM)[lane];
  float t0 = bf2f(ta[0]), t1 = bf2f(ta[1]), t2 = bf2f(ta[2]), t3 = bf2f(ta[3]);

  int j0 = sidx[(size_t)i * 3 + 0];
  int j1 = sidx[(size_t)i * 3 + 1];
  int j2 = sidx[(size_t)i * 3 + 2];
  bool v0 = (j0 >= 0) & (j0 < BDIM) & (j0 != i);
  bool v1 = (j1 >= 0) & (j1 < BDIM) & (j1 != i) & !(v0 & (j1 == j0));
  bool v2 = (j2 >= 0) & (j2 < BDIM) & (j2 != i) & !(v0 & (j2 == j0)) &
            !(v1 & (j2 == j1));

  float corr = 0.0f;
  {  // diagonal
    u16x4 va = reinterpret_cast<const u16x4*>(vn + (size_t)i * DDIM)[lane];
    float d = t0 * bf2f(va[0]) + t1 * bf2f(va[1]) + t2 * bf2f(va[2]) +
              t3 * bf2f(va[3]);
    #pragma unroll
    for (int off = 1; off < 64; off <<= 1) d += __shfl_xor(d, off, 64);
    float u = fmaxf(d, 0.0f);
    corr += (d - 1.0f) * (d - 1.0f) - 0.7f * u * u;
  }
  int jj[3] = {j0, j1, j2};
  bool vv[3] = {v0, v1, v2};
  #pragma unroll
  for (int k = 0; k < 3; ++k) {
    int j = vv[k] ? jj[k] : i;  // safe address; discarded if invalid
    u16x4 va = reinterpret_cast<const u16x4*>(vn + (size_t)j * DDIM)[lane];
    float d = t0 * bf2f(va[0]) + t1 * bf2f(va[1]) + t2 * bf2f(va[2]) +
              t3 * bf2f(va[3]);
    #pragma unroll
    for (int off = 1; off < 64; off <<= 1) d += __shfl_xor(d, off, 64);
    if (vv[k]) {
      float up = fmaxf(0.7f - d, 0.0f);
      float un = fmaxf(d, 0.0f);
      corr += 0.7f * (up * up - un * un);
    }
  }
  if (lane == 0) atomicAdd(&slots[i & (NSLOTS - 1)], corr);
}

// ---------------------------------------------------------------------------
// Kernel 4: sum the 512 slots -> out (plain store).
// ---------------------------------------------------------------------------
__global__ __launch_bounds__(256) void reduce_kernel(
    const float* __restrict__ slots, float* __restrict__ out) {
  __shared__ float rb[4];
  int tid = threadIdx.x;
  float s = slots[tid] + slots[tid + 256];
  #pragma unroll
  for (int off = 1; off < 64; off <<= 1) s += __shfl_xor(s, off, 64);
  if ((tid & 63) == 0) rb[tid >> 6] = s;
  __syncthreads();
  if (tid == 0) out[0] = rb[0] + rb[1] + rb[2] + rb[3];
}

extern "C" void kernel_launch(void* const* d_in, const int* in_sizes, int n_in,
                              void* d_out, int out_size, void* d_ws,
                              size_t ws_size, hipStream_t stream) {
  const float* t = (const float*)d_in[0];
  const float* v = (const float*)d_in[1];
  const int* sidx = (const int*)d_in[2];
  float* out = (float*)d_out;
  float* slots = (float*)d_ws;  // 512 floats
  unsigned short* tn = (unsigned short*)((char*)d_ws + 4096);  // 4 MB
  unsigned short* vn = tn + (size_t)BDIM * DDIM;               // 4 MB

  hipMemsetAsync(slots, 0, NSLOTS * sizeof(float), stream);
  norm_convert_kernel<<<4096, 256, 0, stream>>>(t, v, tn, vn);
  loss_kernel<<<1024, 512, 0, stream>>>(tn, vn, slots);
  corr_kernel<<<2048, 256, 0, stream>>>(tn, vn, sidx, slots);
  reduce_kernel<<<1, 256, 0, stream>>>(slots, out);
}

// Round 4
// 61.112 us; speedup vs baseline: 1.1423x; 1.1423x over previous
//
#include <hip/hip_runtime.h>

#define BDIM 8192
#define DDIM 256
#define NSLOTS 512

typedef __bf16 bf16x8 __attribute__((ext_vector_type(8)));
typedef float f32x4 __attribute__((ext_vector_type(4)));
typedef unsigned short u16x4 __attribute__((ext_vector_type(4)));

#define MEMF() asm volatile("" ::: "memory")
#define BARR()                       \
  do {                               \
    MEMF();                          \
    __builtin_amdgcn_s_barrier();    \
    MEMF();                          \
  } while (0)
#define VMW(n) asm volatile("s_waitcnt vmcnt(" #n ")" ::: "memory")

__device__ inline unsigned short f2bf(float f) {
  unsigned u = __float_as_uint(f);
  u += 0x7FFFu + ((u >> 16) & 1u);  // round-to-nearest-even
  return (unsigned short)(u >> 16);
}
__device__ inline float bf2f(unsigned short h) {
  return __uint_as_float(((unsigned)h) << 16);
}

// Direct global->LDS DMA, 16B/lane. LDS operand = wave-uniform base; HW
// scatters lane*16. Global source is per-lane (carries the swizzle).
__device__ inline void gload_lds16(const void* g, void* l) {
  __builtin_amdgcn_global_load_lds(
      (const __attribute__((address_space(1))) void*)g,
      (__attribute__((address_space(3))) void*)l, 16, 0, 0);
}

// ---------------------------------------------------------------------------
// Kernel 1: normalize rows and convert to bf16, once. One wave per row.
// Block 0 additionally zeroes the reduction slots (replaces a memset
// dispatch; loss/corr only launch after this kernel completes).
// ---------------------------------------------------------------------------
__global__ __launch_bounds__(256) void norm_convert_kernel(
    const float* __restrict__ t, const float* __restrict__ v,
    unsigned short* __restrict__ tn, unsigned short* __restrict__ vn,
    float* __restrict__ slots) {
  int wid = threadIdx.x >> 6, lane = threadIdx.x & 63;
  if (blockIdx.x == 0) {
    slots[threadIdx.x] = 0.0f;
    slots[threadIdx.x + 256] = 0.0f;
  }
  int row = blockIdx.x * 4 + wid;
  const float* src;
  unsigned short* dst;
  if (row < BDIM) {
    src = t + (size_t)row * DDIM;
    dst = tn + (size_t)row * DDIM;
  } else {
    int r = row - BDIM;
    src = v + (size_t)r * DDIM;
    dst = vn + (size_t)r * DDIM;
  }
  float4 x = reinterpret_cast<const float4*>(src)[lane];
  float ss = x.x * x.x + x.y * x.y + x.z * x.z + x.w * x.w;
  #pragma unroll
  for (int off = 1; off < 64; off <<= 1) ss += __shfl_xor(ss, off, 64);
  float sc = 1.0f / fmaxf(sqrtf(ss), 1e-12f);
  u16x4 w;
  w[0] = f2bf(x.x * sc); w[1] = f2bf(x.y * sc);
  w[2] = f2bf(x.z * sc); w[3] = f2bf(x.w * sc);
  reinterpret_cast<u16x4*>(dst)[lane] = w;
}

// ---------------------------------------------------------------------------
// Kernel 2: 256x256-tile bf16 GEMM, 8 waves (2Mx4N), BK=64, 4 phases per
// K-tile (quadrant order (0,0),(0,1),(1,1),(1,0)) with FRAGMENT REUSE:
//   P1: read A(mh=0) 8 + B(nh=0) 4 -> MFMA Q00
//   P2: read B(nh=1) 4             -> MFMA Q01   (A reused)
//   P3: read A(mh=1) 8             -> MFMA Q11   (bv1 reused)
//   P4: no reads                   -> MFMA Q10   (bv0 reused)
// 24 ds_read_b128 per K-tile per wave (was 48). No explicit lgkmcnt(0):
// compiler emits counted per-use waits so MFMA overlaps the read tail.
// Staging: 2 gload_lds/phase into the opposite (dead) buffer; counted vmcnt
// (never 0 in steady state): VMW(4) end-P2 covers this tile's A1/A3;
// VMW(2) end-P4 covers next tile's B0-3,A0,A2. setprio around MFMA cluster.
//
// LDS swizzle (involution, both sides): granule' = granule ^ (row&7) on the
// per-lane GLOBAL source (DMA dest linear) and on the ds_read address.
// ---------------------------------------------------------------------------
__global__ __launch_bounds__(512) void loss_kernel(
    const unsigned short* __restrict__ tn,
    const unsigned short* __restrict__ vn, float* __restrict__ slots) {
  __shared__ unsigned short Asb[2][16384];  // [buf][256 rows][64 cols]
  __shared__ unsigned short Bsb[2][16384];
  __shared__ float rbuf[8];

  const int tid = threadIdx.x;
  const int lane = tid & 63;
  const int wid = tid >> 6;
  const int l15 = lane & 15;
  const int l4 = lane >> 4;
  const int wm = wid >> 2;  // 0..1: wave's 128-row half
  const int wn = wid & 3;   // 0..3: wave's 64-col quarter

  // XCD-aware bijective swizzle: 1024 blocks, 8 XCDs, 128 blocks/XCD.
  const int flat = blockIdx.x;
  const int nb = (flat & 7) * 128 + (flat >> 3);
  const int rowBase = (nb >> 5) * 256;
  const int colBase = (nb & 31) * 256;

  // Staging: one region = 64 rows (512 threads x 16B = 8KB).
  const int sg = (tid & 7) ^ ((tid >> 3) & 7);
  const unsigned short* gAsrc =
      tn + (size_t)(rowBase + (tid >> 3)) * DDIM + sg * 8;
  const unsigned short* gBsrc =
      vn + (size_t)(colBase + (tid >> 3)) * DDIM + sg * 8;
  const int ldsStage = wid * 512;  // shorts; wave-uniform base

  auto stA = [&](int ob, int rg, int kt) {
    gload_lds16(gAsrc + (size_t)rg * 64 * DDIM + kt * 64,
                &Asb[ob][rg * 4096 + ldsStage]);
  };
  auto stB = [&](int ob, int rg, int kt) {
    gload_lds16(gBsrc + (size_t)rg * 64 * DDIM + kt * 64,
                &Bsb[ob][rg * 4096 + ldsStage]);
  };

  f32x4 acc[8][4];
  #pragma unroll
  for (int i = 0; i < 8; ++i)
    #pragma unroll
    for (int j = 0; j < 4; ++j) acc[i][j] = (f32x4)(0.0f);

  bf16x8 af[4][2], bv0[2][2], bv1[2][2];

  auto readA = [&](int cur, int mh) {
    #pragma unroll
    for (int mm = 0; mm < 4; ++mm) {
      const int row = wm * 128 + (mh * 4 + mm) * 16 + l15;  // row&7==l15&7
      #pragma unroll
      for (int kk = 0; kk < 2; ++kk) {
        const int gg = (kk * 4 + l4) ^ (l15 & 7);
        af[mm][kk] =
            *reinterpret_cast<const bf16x8*>(&Asb[cur][row * 64 + gg * 8]);
      }
    }
  };
  auto readB = [&](int cur, int nh, bf16x8 (&bv)[2][2]) {
    #pragma unroll
    for (int nn = 0; nn < 2; ++nn) {
      const int row = wn * 64 + (nh * 2 + nn) * 16 + l15;
      #pragma unroll
      for (int kk = 0; kk < 2; ++kk) {
        const int gg = (kk * 4 + l4) ^ (l15 & 7);
        bv[nn][kk] =
            *reinterpret_cast<const bf16x8*>(&Bsb[cur][row * 64 + gg * 8]);
      }
    }
  };
  auto mfmaQ = [&](int mh, int nh, bf16x8 (&bv)[2][2]) {
    __builtin_amdgcn_s_setprio(1);
    #pragma unroll
    for (int mm = 0; mm < 4; ++mm)
      #pragma unroll
      for (int nn = 0; nn < 2; ++nn)
        #pragma unroll
        for (int kk = 0; kk < 2; ++kk)
          acc[mh * 4 + mm][nh * 2 + nn] =
              __builtin_amdgcn_mfma_f32_16x16x32_bf16(
                  af[mm][kk], bv[nn][kk], acc[mh * 4 + mm][nh * 2 + nn], 0, 0,
                  0);
    __builtin_amdgcn_s_setprio(0);
  };

  // Prologue: tile 0 into buf0, A1/A3 last; keep them in flight (vmcnt(2)).
  stB(0, 0, 0); stB(0, 1, 0); stB(0, 2, 0); stB(0, 3, 0);
  stA(0, 0, 0); stA(0, 2, 0);
  stA(0, 1, 0); stA(0, 3, 0);
  VMW(2);
  BARR();

  #pragma unroll
  for (int t = 0; t < 4; ++t) {  // K-tiles (K=256, BK=64)
    const int cur = t & 1, ob = cur ^ 1, kt = t + 1;
    // ---- P1: quadrant (0,0) ----
    readA(cur, 0);
    readB(cur, 0, bv0);
    if (t < 3) { stB(ob, 0, kt); stB(ob, 1, kt); }
    BARR();
    mfmaQ(0, 0, bv0);
    BARR();
    // ---- P2: quadrant (0,1) ----
    readB(cur, 1, bv1);
    if (t < 3) { stB(ob, 2, kt); stB(ob, 3, kt); VMW(4); } else { VMW(0); }
    BARR();
    mfmaQ(0, 1, bv1);
    BARR();
    // ---- P3: quadrant (1,1) ----
    readA(cur, 1);
    if (t < 3) { stA(ob, 0, kt); stA(ob, 2, kt); }
    BARR();
    mfmaQ(1, 1, bv1);
    BARR();
    // ---- P4: quadrant (1,0) ----
    if (t < 3) { stA(ob, 1, kt); stA(ob, 3, kt); VMW(2); }
    BARR();
    mfmaQ(1, 0, bv0);
    BARR();
  }

  // Position-blind epilogue: 0.7*max(s,0)^2 for every element.
  float lsum = 0.0f;
  #pragma unroll
  for (int m = 0; m < 8; ++m)
    #pragma unroll
    for (int n = 0; n < 4; ++n)
      #pragma unroll
      for (int r = 0; r < 4; ++r) {
        float u = fmaxf(acc[m][n][r], 0.0f);
        lsum = fmaf(u, u, lsum);
      }
  lsum *= 0.7f;  // LAMBDA_NEG
  #pragma unroll
  for (int off = 1; off < 64; off <<= 1) lsum += __shfl_xor(lsum, off, 64);
  if (lane == 0) rbuf[wid] = lsum;
  __syncthreads();
  if (tid == 0) {
    float s = 0.0f;
    #pragma unroll
    for (int w = 0; w < 8; ++w) s += rbuf[w];
    atomicAdd(&slots[flat & (NSLOTS - 1)], s);
  }
}

// ---------------------------------------------------------------------------
// Kernel 3: sparse fixups, one wave per row. Diagonal: replace
// 0.7*max(s,0)^2 with (s-1)^2; each dedup'd valid semi j: replace with
// 0.7*max(0.7-s,0)^2. Same bf16 inputs + fp32 accum as the MFMA path.
// ---------------------------------------------------------------------------
__global__ __launch_bounds__(256) void corr_kernel(
    const unsigned short* __restrict__ tn,
    const unsigned short* __restrict__ vn, const int* __restrict__ sidx,
    float* __restrict__ slots) {
  int wid = threadIdx.x >> 6, lane = threadIdx.x & 63;
  int i = blockIdx.x * 4 + wid;

  u16x4 ta = reinterpret_cast<const u16x4*>(tn + (size_t)i * DDIM)[lane];
  float t0 = bf2f(ta[0]), t1 = bf2f(ta[1]), t2 = bf2f(ta[2]), t3 = bf2f(ta[3]);

  int j0 = sidx[(size_t)i * 3 + 0];
  int j1 = sidx[(size_t)i * 3 + 1];
  int j2 = sidx[(size_t)i * 3 + 2];
  bool v0 = (j0 >= 0) & (j0 < BDIM) & (j0 != i);
  bool v1 = (j1 >= 0) & (j1 < BDIM) & (j1 != i) & !(v0 & (j1 == j0));
  bool v2 = (j2 >= 0) & (j2 < BDIM) & (j2 != i) & !(v0 & (j2 == j0)) &
            !(v1 & (j2 == j1));

  float corr = 0.0f;
  {  // diagonal
    u16x4 va = reinterpret_cast<const u16x4*>(vn + (size_t)i * DDIM)[lane];
    float d = t0 * bf2f(va[0]) + t1 * bf2f(va[1]) + t2 * bf2f(va[2]) +
              t3 * bf2f(va[3]);
    #pragma unroll
    for (int off = 1; off < 64; off <<= 1) d += __shfl_xor(d, off, 64);
    float u = fmaxf(d, 0.0f);
    corr += (d - 1.0f) * (d - 1.0f) - 0.7f * u * u;
  }
  int jj[3] = {j0, j1, j2};
  bool vv[3] = {v0, v1, v2};
  #pragma unroll
  for (int k = 0; k < 3; ++k) {
    int j = vv[k] ? jj[k] : i;  // safe address; discarded if invalid
    u16x4 va = reinterpret_cast<const u16x4*>(vn + (size_t)j * DDIM)[lane];
    float d = t0 * bf2f(va[0]) + t1 * bf2f(va[1]) + t2 * bf2f(va[2]) +
              t3 * bf2f(va[3]);
    #pragma unroll
    for (int off = 1; off < 64; off <<= 1) d += __shfl_xor(d, off, 64);
    if (vv[k]) {
      float up = fmaxf(0.7f - d, 0.0f);
      float un = fmaxf(d, 0.0f);
      corr += 0.7f * (up * up - un * un);
    }
  }
  if (lane == 0) atomicAdd(&slots[i & (NSLOTS - 1)], corr);
}

// ---------------------------------------------------------------------------
// Kernel 4: sum the 512 slots -> out (plain store).
// ---------------------------------------------------------------------------
__global__ __launch_bounds__(256) void reduce_kernel(
    const float* __restrict__ slots, float* __restrict__ out) {
  __shared__ float rb[4];
  int tid = threadIdx.x;
  float s = slots[tid] + slots[tid + 256];
  #pragma unroll
  for (int off = 1; off < 64; off <<= 1) s += __shfl_xor(s, off, 64);
  if ((tid & 63) == 0) rb[tid >> 6] = s;
  __syncthreads();
  if (tid == 0) out[0] = rb[0] + rb[1] + rb[2] + rb[3];
}

extern "C" void kernel_launch(void* const* d_in, const int* in_sizes, int n_in,
                              void* d_out, int out_size, void* d_ws,
                              size_t ws_size, hipStream_t stream) {
  const float* t = (const float*)d_in[0];
  const float* v = (const float*)d_in[1];
  const int* sidx = (const int*)d_in[2];
  float* out = (float*)d_out;
  float* slots = (float*)d_ws;  // 512 floats
  unsigned short* tn = (unsigned short*)((char*)d_ws + 4096);  // 4 MB
  unsigned short* vn = tn + (size_t)BDIM * DDIM;               // 4 MB

  norm_convert_kernel<<<4096, 256, 0, stream>>>(t, v, tn, vn, slots);
  loss_kernel<<<1024, 512, 0, stream>>>(tn, vn, slots);
  corr_kernel<<<2048, 256, 0, stream>>>(tn, vn, sidx, slots);
  reduce_kernel<<<1, 256, 0, stream>>>(slots, out);
}

// Round 5
// 58.568 us; speedup vs baseline: 1.1919x; 1.0434x over previous
//
#include <hip/hip_runtime.h>

#define BDIM 8192
#define DDIM 256
#define NSLOTS 512

typedef __bf16 bf16x8 __attribute__((ext_vector_type(8)));
typedef float f32x4 __attribute__((ext_vector_type(4)));
typedef unsigned short u16x4 __attribute__((ext_vector_type(4)));

#define MEMF() asm volatile("" ::: "memory")
#define BARR()                       \
  do {                               \
    MEMF();                          \
    __builtin_amdgcn_s_barrier();    \
    MEMF();                          \
  } while (0)
#define VMW(n) asm volatile("s_waitcnt vmcnt(" #n ")" ::: "memory")

__device__ inline unsigned short f2bf(float f) {
  unsigned u = __float_as_uint(f);
  u += 0x7FFFu + ((u >> 16) & 1u);  // round-to-nearest-even
  return (unsigned short)(u >> 16);
}
__device__ inline float bf2f(unsigned short h) {
  return __uint_as_float(((unsigned)h) << 16);
}

// Direct global->LDS DMA, 16B/lane. LDS operand = wave-uniform base; HW
// scatters lane*16. Global source is per-lane (carries the swizzle).
__device__ inline void gload_lds16(const void* g, void* l) {
  __builtin_amdgcn_global_load_lds(
      (const __attribute__((address_space(1))) void*)g,
      (__attribute__((address_space(3))) void*)l, 16, 0, 0);
}

// ---------------------------------------------------------------------------
// Kernel 1: normalize rows and convert to bf16, once. One wave per row.
// Block 0 additionally zeroes the reduction slots.
// ---------------------------------------------------------------------------
__global__ __launch_bounds__(256) void norm_convert_kernel(
    const float* __restrict__ t, const float* __restrict__ v,
    unsigned short* __restrict__ tn, unsigned short* __restrict__ vn,
    float* __restrict__ slots) {
  int wid = threadIdx.x >> 6, lane = threadIdx.x & 63;
  if (blockIdx.x == 0) {
    slots[threadIdx.x] = 0.0f;
    slots[threadIdx.x + 256] = 0.0f;
  }
  int row = blockIdx.x * 4 + wid;
  const float* src;
  unsigned short* dst;
  if (row < BDIM) {
    src = t + (size_t)row * DDIM;
    dst = tn + (size_t)row * DDIM;
  } else {
    int r = row - BDIM;
    src = v + (size_t)r * DDIM;
    dst = vn + (size_t)r * DDIM;
  }
  float4 x = reinterpret_cast<const float4*>(src)[lane];
  float ss = x.x * x.x + x.y * x.y + x.z * x.z + x.w * x.w;
  #pragma unroll
  for (int off = 1; off < 64; off <<= 1) ss += __shfl_xor(ss, off, 64);
  float sc = 1.0f / fmaxf(sqrtf(ss), 1e-12f);
  u16x4 w;
  w[0] = f2bf(x.x * sc); w[1] = f2bf(x.y * sc);
  w[2] = f2bf(x.z * sc); w[3] = f2bf(x.w * sc);
  reinterpret_cast<u16x4*>(dst)[lane] = w;
}

// ---------------------------------------------------------------------------
// Kernel 2: 256x256-tile bf16 GEMM, 8 waves (2Mx4N), BK=64, ONE barrier per
// K-tile. Within a tile, reads come from buf `cur` and staging DMAs target
// buf `ob` (disjoint) -> no intra-tile hazard, so no intra-tile barriers:
// the two waves per SIMD skew freely and cross-cover LDS reads vs MFMA
// (round-4's 8-barriers-per-tile lockstep serialized them; 44.5us at
// MfmaUtil 28%). Fragment reuse: A read once per mh-half, B halves kept
// live in regs across quadrants -> 24 ds_read_b128 / K-tile / wave.
// Tile boundary: VMW(0)+BARR. The staged loads were issued a full tile
// (~3k cyc >> 900 cyc HBM latency) earlier, so vmcnt(0) is residual-only
// (issue-early/drain-late, not drain-after-issue). The tile-start barrier
// also separates tile t-1's reads of buffer parity cur(t+1) (drained by
// the lgkm waits of t-1's MFMAs, which precede the barrier) from tile t's
// staging into it.
//
// LDS swizzle (involution, both sides): granule' = granule ^ (row&7) on the
// per-lane GLOBAL source (DMA dest linear) and on the ds_read address.
// ---------------------------------------------------------------------------
__global__ __launch_bounds__(512) void loss_kernel(
    const unsigned short* __restrict__ tn,
    const unsigned short* __restrict__ vn, float* __restrict__ slots) {
  __shared__ unsigned short Asb[2][16384];  // [buf][256 rows][64 cols]
  __shared__ unsigned short Bsb[2][16384];
  __shared__ float rbuf[8];

  const int tid = threadIdx.x;
  const int lane = tid & 63;
  const int wid = tid >> 6;
  const int l15 = lane & 15;
  const int l4 = lane >> 4;
  const int wm = wid >> 2;  // 0..1: wave's 128-row half
  const int wn = wid & 3;   // 0..3: wave's 64-col quarter

  // XCD-aware bijective swizzle: 1024 blocks, 8 XCDs, 128 blocks/XCD.
  const int flat = blockIdx.x;
  const int nb = (flat & 7) * 128 + (flat >> 3);
  const int rowBase = (nb >> 5) * 256;
  const int colBase = (nb & 31) * 256;

  // Staging: one region = 64 rows (512 threads x 16B = 8KB).
  const int sg = (tid & 7) ^ ((tid >> 3) & 7);
  const unsigned short* gAsrc =
      tn + (size_t)(rowBase + (tid >> 3)) * DDIM + sg * 8;
  const unsigned short* gBsrc =
      vn + (size_t)(colBase + (tid >> 3)) * DDIM + sg * 8;
  const int ldsStage = wid * 512;  // shorts; wave-uniform base

  auto stA = [&](int ob, int rg, int kt) {
    gload_lds16(gAsrc + (size_t)rg * 64 * DDIM + kt * 64,
                &Asb[ob][rg * 4096 + ldsStage]);
  };
  auto stB = [&](int ob, int rg, int kt) {
    gload_lds16(gBsrc + (size_t)rg * 64 * DDIM + kt * 64,
                &Bsb[ob][rg * 4096 + ldsStage]);
  };

  f32x4 acc[8][4];
  #pragma unroll
  for (int i = 0; i < 8; ++i)
    #pragma unroll
    for (int j = 0; j < 4; ++j) acc[i][j] = (f32x4)(0.0f);

  bf16x8 af[4][2], bv0[2][2], bv1[2][2];

  auto readA = [&](int cur, int mh) {
    #pragma unroll
    for (int mm = 0; mm < 4; ++mm) {
      const int row = wm * 128 + (mh * 4 + mm) * 16 + l15;  // row&7==l15&7
      #pragma unroll
      for (int kk = 0; kk < 2; ++kk) {
        const int gg = (kk * 4 + l4) ^ (l15 & 7);
        af[mm][kk] =
            *reinterpret_cast<const bf16x8*>(&Asb[cur][row * 64 + gg * 8]);
      }
    }
  };
  auto readB = [&](int cur, int nh, bf16x8 (&bv)[2][2]) {
    #pragma unroll
    for (int nn = 0; nn < 2; ++nn) {
      const int row = wn * 64 + (nh * 2 + nn) * 16 + l15;
      #pragma unroll
      for (int kk = 0; kk < 2; ++kk) {
        const int gg = (kk * 4 + l4) ^ (l15 & 7);
        bv[nn][kk] =
            *reinterpret_cast<const bf16x8*>(&Bsb[cur][row * 64 + gg * 8]);
      }
    }
  };
  auto mfmaQ = [&](int mh, int nh, bf16x8 (&bv)[2][2]) {
    __builtin_amdgcn_s_setprio(1);
    #pragma unroll
    for (int mm = 0; mm < 4; ++mm)
      #pragma unroll
      for (int nn = 0; nn < 2; ++nn)
        #pragma unroll
        for (int kk = 0; kk < 2; ++kk)
          acc[mh * 4 + mm][nh * 2 + nn] =
              __builtin_amdgcn_mfma_f32_16x16x32_bf16(
                  af[mm][kk], bv[nn][kk], acc[mh * 4 + mm][nh * 2 + nn], 0, 0,
                  0);
    __builtin_amdgcn_s_setprio(0);
  };

  // Prologue: stage tile 0 into buf0, drain, barrier.
  stB(0, 0, 0); stB(0, 1, 0); stB(0, 2, 0); stB(0, 3, 0);
  stA(0, 0, 0); stA(0, 1, 0); stA(0, 2, 0); stA(0, 3, 0);
  VMW(0);
  BARR();

  #pragma unroll
  for (int t = 0; t < 4; ++t) {  // K-tiles (K=256, BK=64)
    const int cur = t & 1, ob = cur ^ 1, kt = t + 1;
    // Issue-early: all 8 prefetch DMAs for tile t+1 (dead buffer).
    if (t < 3) {
      stB(ob, 0, kt); stB(ob, 1, kt); stB(ob, 2, kt); stB(ob, 3, kt);
      stA(ob, 0, kt); stA(ob, 1, kt); stA(ob, 2, kt); stA(ob, 3, kt);
    }
    // Straight-line reads + MFMA; compiler emits counted lgkmcnt, the two
    // skewed waves per SIMD cross-cover LDS vs MFMA.
    readA(cur, 0);
    readB(cur, 0, bv0);
    readB(cur, 1, bv1);
    mfmaQ(0, 0, bv0);
    mfmaQ(0, 1, bv1);
    readA(cur, 1);
    mfmaQ(1, 1, bv1);
    mfmaQ(1, 0, bv0);
    // Tile boundary: next tile's staging must be complete in every wave.
    if (t < 3) {
      VMW(0);
      BARR();
    }
  }

  // Position-blind epilogue: 0.7*max(s,0)^2 for every element.
  float lsum = 0.0f;
  #pragma unroll
  for (int m = 0; m < 8; ++m)
    #pragma unroll
    for (int n = 0; n < 4; ++n)
      #pragma unroll
      for (int r = 0; r < 4; ++r) {
        float u = fmaxf(acc[m][n][r], 0.0f);
        lsum = fmaf(u, u, lsum);
      }
  lsum *= 0.7f;  // LAMBDA_NEG
  #pragma unroll
  for (int off = 1; off < 64; off <<= 1) lsum += __shfl_xor(lsum, off, 64);
  if (lane == 0) rbuf[wid] = lsum;
  __syncthreads();
  if (tid == 0) {
    float s = 0.0f;
    #pragma unroll
    for (int w = 0; w < 8; ++w) s += rbuf[w];
    atomicAdd(&slots[flat & (NSLOTS - 1)], s);
  }
}

// ---------------------------------------------------------------------------
// Kernel 3: sparse fixups, one wave per row. Diagonal: replace
// 0.7*max(s,0)^2 with (s-1)^2; each dedup'd valid semi j: replace with
// 0.7*max(0.7-s,0)^2. Same bf16 inputs + fp32 accum as the MFMA path.
// ---------------------------------------------------------------------------
__global__ __launch_bounds__(256) void corr_kernel(
    const unsigned short* __restrict__ tn,
    const unsigned short* __restrict__ vn, const int* __restrict__ sidx,
    float* __restrict__ slots) {
  int wid = threadIdx.x >> 6, lane = threadIdx.x & 63;
  int i = blockIdx.x * 4 + wid;

  u16x4 ta = reinterpret_cast<const u16x4*>(tn + (size_t)i * DDIM)[lane];
  float t0 = bf2f(ta[0]), t1 = bf2f(ta[1]), t2 = bf2f(ta[2]), t3 = bf2f(ta[3]);

  int j0 = sidx[(size_t)i * 3 + 0];
  int j1 = sidx[(size_t)i * 3 + 1];
  int j2 = sidx[(size_t)i * 3 + 2];
  bool v0 = (j0 >= 0) & (j0 < BDIM) & (j0 != i);
  bool v1 = (j1 >= 0) & (j1 < BDIM) & (j1 != i) & !(v0 & (j1 == j0));
  bool v2 = (j2 >= 0) & (j2 < BDIM) & (j2 != i) & !(v0 & (j2 == j0)) &
            !(v1 & (j2 == j1));

  float corr = 0.0f;
  {  // diagonal
    u16x4 va = reinterpret_cast<const u16x4*>(vn + (size_t)i * DDIM)[lane];
    float d = t0 * bf2f(va[0]) + t1 * bf2f(va[1]) + t2 * bf2f(va[2]) +
              t3 * bf2f(va[3]);
    #pragma unroll
    for (int off = 1; off < 64; off <<= 1) d += __shfl_xor(d, off, 64);
    float u = fmaxf(d, 0.0f);
    corr += (d - 1.0f) * (d - 1.0f) - 0.7f * u * u;
  }
  int jj[3] = {j0, j1, j2};
  bool vv[3] = {v0, v1, v2};
  #pragma unroll
  for (int k = 0; k < 3; ++k) {
    int j = vv[k] ? jj[k] : i;  // safe address; discarded if invalid
    u16x4 va = reinterpret_cast<const u16x4*>(vn + (size_t)j * DDIM)[lane];
    float d = t0 * bf2f(va[0]) + t1 * bf2f(va[1]) + t2 * bf2f(va[2]) +
              t3 * bf2f(va[3]);
    #pragma unroll
    for (int off = 1; off < 64; off <<= 1) d += __shfl_xor(d, off, 64);
    if (vv[k]) {
      float up = fmaxf(0.7f - d, 0.0f);
      float un = fmaxf(d, 0.0f);
      corr += 0.7f * (up * up - un * un);
    }
  }
  if (lane == 0) atomicAdd(&slots[i & (NSLOTS - 1)], corr);
}

// ---------------------------------------------------------------------------
// Kernel 4: sum the 512 slots -> out (plain store).
// ---------------------------------------------------------------------------
__global__ __launch_bounds__(256) void reduce_kernel(
    const float* __restrict__ slots, float* __restrict__ out) {
  __shared__ float rb[4];
  int tid = threadIdx.x;
  float s = slots[tid] + slots[tid + 256];
  #pragma unroll
  for (int off = 1; off < 64; off <<= 1) s += __shfl_xor(s, off, 64);
  if ((tid & 63) == 0) rb[tid >> 6] = s;
  __syncthreads();
  if (tid == 0) out[0] = rb[0] + rb[1] + rb[2] + rb[3];
}

extern "C" void kernel_launch(void* const* d_in, const int* in_sizes, int n_in,
                              void* d_out, int out_size, void* d_ws,
                              size_t ws_size, hipStream_t stream) {
  const float* t = (const float*)d_in[0];
  const float* v = (const float*)d_in[1];
  const int* sidx = (const int*)d_in[2];
  float* out = (float*)d_out;
  float* slots = (float*)d_ws;  // 512 floats
  unsigned short* tn = (unsigned short*)((char*)d_ws + 4096);  // 4 MB
  unsigned short* vn = tn + (size_t)BDIM * DDIM;               // 4 MB

  norm_convert_kernel<<<4096, 256, 0, stream>>>(t, v, tn, vn, slots);
  loss_kernel<<<1024, 512, 0, stream>>>(tn, vn, slots);
  corr_kernel<<<2048, 256, 0, stream>>>(tn, vn, sidx, slots);
  reduce_kernel<<<1, 256, 0, stream>>>(slots, out);
}

// Round 6
// 56.416 us; speedup vs baseline: 1.2374x; 1.0381x over previous
//
#include <hip/hip_runtime.h>

#define BDIM 8192
#define DDIM 256
#define NSLOTS 512

typedef __bf16 bf16x8 __attribute__((ext_vector_type(8)));
typedef float f32x4 __attribute__((ext_vector_type(4)));
typedef unsigned short u16x4 __attribute__((ext_vector_type(4)));

#define MEMF() asm volatile("" ::: "memory")
#define BARR()                       \
  do {                               \
    MEMF();                          \
    __builtin_amdgcn_s_barrier();    \
    MEMF();                          \
  } while (0)
#define VMW(n) asm volatile("s_waitcnt vmcnt(" #n ")" ::: "memory")

__device__ inline unsigned short f2bf(float f) {
  unsigned u = __float_as_uint(f);
  u += 0x7FFFu + ((u >> 16) & 1u);  // round-to-nearest-even
  return (unsigned short)(u >> 16);
}
__device__ inline float bf2f(unsigned short h) {
  return __uint_as_float(((unsigned)h) << 16);
}

// Direct global->LDS DMA, 16B/lane. LDS operand = wave-uniform base; HW
// scatters lane*16. Global source is per-lane (carries the swizzle).
__device__ inline void gload_lds16(const void* g, void* l) {
  __builtin_amdgcn_global_load_lds(
      (const __attribute__((address_space(1))) void*)g,
      (__attribute__((address_space(3))) void*)l, 16, 0, 0);
}

// ---------------------------------------------------------------------------
// Kernel 1: normalize rows and convert to bf16, once. One wave per row.
// Block 0 additionally zeroes the reduction slots.
// ---------------------------------------------------------------------------
__global__ __launch_bounds__(256) void norm_convert_kernel(
    const float* __restrict__ t, const float* __restrict__ v,
    unsigned short* __restrict__ tn, unsigned short* __restrict__ vn,
    float* __restrict__ slots) {
  int wid = threadIdx.x >> 6, lane = threadIdx.x & 63;
  if (blockIdx.x == 0) {
    slots[threadIdx.x] = 0.0f;
    slots[threadIdx.x + 256] = 0.0f;
  }
  int row = blockIdx.x * 4 + wid;
  const float* src;
  unsigned short* dst;
  if (row < BDIM) {
    src = t + (size_t)row * DDIM;
    dst = tn + (size_t)row * DDIM;
  } else {
    int r = row - BDIM;
    src = v + (size_t)r * DDIM;
    dst = vn + (size_t)r * DDIM;
  }
  float4 x = reinterpret_cast<const float4*>(src)[lane];
  float ss = x.x * x.x + x.y * x.y + x.z * x.z + x.w * x.w;
  #pragma unroll
  for (int off = 1; off < 64; off <<= 1) ss += __shfl_xor(ss, off, 64);
  float sc = 1.0f / fmaxf(sqrtf(ss), 1e-12f);
  u16x4 w;
  w[0] = f2bf(x.x * sc); w[1] = f2bf(x.y * sc);
  w[2] = f2bf(x.z * sc); w[3] = f2bf(x.w * sc);
  reinterpret_cast<u16x4*>(dst)[lane] = w;
}

// ---------------------------------------------------------------------------
// Kernel 2: 256x256-tile bf16 GEMM, 8 waves (2Mx4N), BK=64, ONE barrier per
// K-tile (round-5 structure unchanged). Fragment reuse: 24 ds_read_b128 per
// K-tile per wave. Issue-early prefetch into the dead buffer; VMW(0)+BARR
// only at tile boundary (residual-only wait: loads had a full tile to land).
//
// ROUND-6 CHANGE: 2D panel-rectangle XCD swizzle. Old 1D swizzle gave each
// XCD-round 1 row-panel x ALL 32 col-panels -> whole 4MB B streamed through
// each XCD's 4MB L2 every round (self-thrash; FETCH_SIZE 40MB = 5x input).
// New mapping: XCD (xi=xcd>>2, xj=xcd&3) owns a 16x8 panel rectangle; round
// r covers a 4x8 sub-rectangle. Per round: A=512KB, B=1MB (fit L2); col-
// panels identical across rounds -> B fetched from L3 once per XCD.
// Bijective: flat <-> (xcd,r,p) <-> (rowp,colp) are bit-field splits.
//
// LDS swizzle (involution, both sides): granule' = granule ^ (row&7) on the
// per-lane GLOBAL source (DMA dest linear) and on the ds_read address.
// ---------------------------------------------------------------------------
__global__ __launch_bounds__(512) void loss_kernel(
    const unsigned short* __restrict__ tn,
    const unsigned short* __restrict__ vn, float* __restrict__ slots) {
  __shared__ unsigned short Asb[2][16384];  // [buf][256 rows][64 cols]
  __shared__ unsigned short Bsb[2][16384];
  __shared__ float rbuf[8];

  const int tid = threadIdx.x;
  const int lane = tid & 63;
  const int wid = tid >> 6;
  const int l15 = lane & 15;
  const int l4 = lane >> 4;
  const int wm = wid >> 2;  // 0..1: wave's 128-row half
  const int wn = wid & 3;   // 0..3: wave's 64-col quarter

  // 2D panel-rectangle XCD swizzle (1024 blocks, 8 XCDs, round-robin
  // dispatch heuristic: xcd = flat & 7).
  const int flat = blockIdx.x;
  const int xcd = flat & 7;
  const int s = flat >> 3;   // 0..127 within XCD
  const int r = s >> 5;      // round 0..3 (32 CUs/XCD)
  const int p = s & 31;      // position in the 4x8 rectangle
  const int rowp = (xcd >> 2) * 16 + r * 4 + (p >> 3);  // 0..31
  const int colp = (xcd & 3) * 8 + (p & 7);             // 0..31
  const int rowBase = rowp * 256;
  const int colBase = colp * 256;

  // Staging: one region = 64 rows (512 threads x 16B = 8KB).
  const int sg = (tid & 7) ^ ((tid >> 3) & 7);
  const unsigned short* gAsrc =
      tn + (size_t)(rowBase + (tid >> 3)) * DDIM + sg * 8;
  const unsigned short* gBsrc =
      vn + (size_t)(colBase + (tid >> 3)) * DDIM + sg * 8;
  const int ldsStage = wid * 512;  // shorts; wave-uniform base

  auto stA = [&](int ob, int rg, int kt) {
    gload_lds16(gAsrc + (size_t)rg * 64 * DDIM + kt * 64,
                &Asb[ob][rg * 4096 + ldsStage]);
  };
  auto stB = [&](int ob, int rg, int kt) {
    gload_lds16(gBsrc + (size_t)rg * 64 * DDIM + kt * 64,
                &Bsb[ob][rg * 4096 + ldsStage]);
  };

  f32x4 acc[8][4];
  #pragma unroll
  for (int i = 0; i < 8; ++i)
    #pragma unroll
    for (int j = 0; j < 4; ++j) acc[i][j] = (f32x4)(0.0f);

  bf16x8 af[4][2], bv0[2][2], bv1[2][2];

  auto readA = [&](int cur, int mh) {
    #pragma unroll
    for (int mm = 0; mm < 4; ++mm) {
      const int row = wm * 128 + (mh * 4 + mm) * 16 + l15;  // row&7==l15&7
      #pragma unroll
      for (int kk = 0; kk < 2; ++kk) {
        const int gg = (kk * 4 + l4) ^ (l15 & 7);
        af[mm][kk] =
            *reinterpret_cast<const bf16x8*>(&Asb[cur][row * 64 + gg * 8]);
      }
    }
  };
  auto readB = [&](int cur, int nh, bf16x8 (&bv)[2][2]) {
    #pragma unroll
    for (int nn = 0; nn < 2; ++nn) {
      const int row = wn * 64 + (nh * 2 + nn) * 16 + l15;
      #pragma unroll
      for (int kk = 0; kk < 2; ++kk) {
        const int gg = (kk * 4 + l4) ^ (l15 & 7);
        bv[nn][kk] =
            *reinterpret_cast<const bf16x8*>(&Bsb[cur][row * 64 + gg * 8]);
      }
    }
  };
  auto mfmaQ = [&](int mh, int nh, bf16x8 (&bv)[2][2]) {
    __builtin_amdgcn_s_setprio(1);
    #pragma unroll
    for (int mm = 0; mm < 4; ++mm)
      #pragma unroll
      for (int nn = 0; nn < 2; ++nn)
        #pragma unroll
        for (int kk = 0; kk < 2; ++kk)
          acc[mh * 4 + mm][nh * 2 + nn] =
              __builtin_amdgcn_mfma_f32_16x16x32_bf16(
                  af[mm][kk], bv[nn][kk], acc[mh * 4 + mm][nh * 2 + nn], 0, 0,
                  0);
    __builtin_amdgcn_s_setprio(0);
  };

  // Prologue: stage tile 0 into buf0, drain, barrier.
  stB(0, 0, 0); stB(0, 1, 0); stB(0, 2, 0); stB(0, 3, 0);
  stA(0, 0, 0); stA(0, 1, 0); stA(0, 2, 0); stA(0, 3, 0);
  VMW(0);
  BARR();

  #pragma unroll
  for (int t = 0; t < 4; ++t) {  // K-tiles (K=256, BK=64)
    const int cur = t & 1, ob = cur ^ 1, kt = t + 1;
    // Issue-early: all 8 prefetch DMAs for tile t+1 (dead buffer).
    if (t < 3) {
      stB(ob, 0, kt); stB(ob, 1, kt); stB(ob, 2, kt); stB(ob, 3, kt);
      stA(ob, 0, kt); stA(ob, 1, kt); stA(ob, 2, kt); stA(ob, 3, kt);
    }
    // Straight-line reads + MFMA; compiler emits counted lgkmcnt, the two
    // skewed waves per SIMD cross-cover LDS vs MFMA.
    readA(cur, 0);
    readB(cur, 0, bv0);
    readB(cur, 1, bv1);
    mfmaQ(0, 0, bv0);
    mfmaQ(0, 1, bv1);
    readA(cur, 1);
    mfmaQ(1, 1, bv1);
    mfmaQ(1, 0, bv0);
    // Tile boundary: next tile's staging must be complete in every wave.
    if (t < 3) {
      VMW(0);
      BARR();
    }
  }

  // Position-blind epilogue: 0.7*max(s,0)^2 for every element.
  float lsum = 0.0f;
  #pragma unroll
  for (int m = 0; m < 8; ++m)
    #pragma unroll
    for (int n = 0; n < 4; ++n)
      #pragma unroll
      for (int r2 = 0; r2 < 4; ++r2) {
        float u = fmaxf(acc[m][n][r2], 0.0f);
        lsum = fmaf(u, u, lsum);
      }
  lsum *= 0.7f;  // LAMBDA_NEG
  #pragma unroll
  for (int off = 1; off < 64; off <<= 1) lsum += __shfl_xor(lsum, off, 64);
  if (lane == 0) rbuf[wid] = lsum;
  __syncthreads();
  if (tid == 0) {
    float sacc = 0.0f;
    #pragma unroll
    for (int w = 0; w < 8; ++w) sacc += rbuf[w];
    atomicAdd(&slots[flat & (NSLOTS - 1)], sacc);
  }
}

// ---------------------------------------------------------------------------
// Kernel 3: sparse fixups, one wave per row. Diagonal: replace
// 0.7*max(s,0)^2 with (s-1)^2; each dedup'd valid semi j: replace with
// 0.7*max(0.7-s,0)^2. Same bf16 inputs + fp32 accum as the MFMA path.
// ---------------------------------------------------------------------------
__global__ __launch_bounds__(256) void corr_kernel(
    const unsigned short* __restrict__ tn,
    const unsigned short* __restrict__ vn, const int* __restrict__ sidx,
    float* __restrict__ slots) {
  int wid = threadIdx.x >> 6, lane = threadIdx.x & 63;
  int i = blockIdx.x * 4 + wid;

  u16x4 ta = reinterpret_cast<const u16x4*>(tn + (size_t)i * DDIM)[lane];
  float t0 = bf2f(ta[0]), t1 = bf2f(ta[1]), t2 = bf2f(ta[2]), t3 = bf2f(ta[3]);

  int j0 = sidx[(size_t)i * 3 + 0];
  int j1 = sidx[(size_t)i * 3 + 1];
  int j2 = sidx[(size_t)i * 3 + 2];
  bool v0 = (j0 >= 0) & (j0 < BDIM) & (j0 != i);
  bool v1 = (j1 >= 0) & (j1 < BDIM) & (j1 != i) & !(v0 & (j1 == j0));
  bool v2 = (j2 >= 0) & (j2 < BDIM) & (j2 != i) & !(v0 & (j2 == j0)) &
            !(v1 & (j2 == j1));

  float corr = 0.0f;
  {  // diagonal
    u16x4 va = reinterpret_cast<const u16x4*>(vn + (size_t)i * DDIM)[lane];
    float d = t0 * bf2f(va[0]) + t1 * bf2f(va[1]) + t2 * bf2f(va[2]) +
              t3 * bf2f(va[3]);
    #pragma unroll
    for (int off = 1; off < 64; off <<= 1) d += __shfl_xor(d, off, 64);
    float u = fmaxf(d, 0.0f);
    corr += (d - 1.0f) * (d - 1.0f) - 0.7f * u * u;
  }
  int jj[3] = {j0, j1, j2};
  bool vv[3] = {v0, v1, v2};
  #pragma unroll
  for (int k = 0; k < 3; ++k) {
    int j = vv[k] ? jj[k] : i;  // safe address; discarded if invalid
    u16x4 va = reinterpret_cast<const u16x4*>(vn + (size_t)j * DDIM)[lane];
    float d = t0 * bf2f(va[0]) + t1 * bf2f(va[1]) + t2 * bf2f(va[2]) +
              t3 * bf2f(va[3]);
    #pragma unroll
    for (int off = 1; off < 64; off <<= 1) d += __shfl_xor(d, off, 64);
    if (vv[k]) {
      float up = fmaxf(0.7f - d, 0.0f);
      float un = fmaxf(d, 0.0f);
      corr += 0.7f * (up * up - un * un);
    }
  }
  if (lane == 0) atomicAdd(&slots[i & (NSLOTS - 1)], corr);
}

// ---------------------------------------------------------------------------
// Kernel 4: sum the 512 slots -> out (plain store).
// ---------------------------------------------------------------------------
__global__ __launch_bounds__(256) void reduce_kernel(
    const float* __restrict__ slots, float* __restrict__ out) {
  __shared__ float rb[4];
  int tid = threadIdx.x;
  float s = slots[tid] + slots[tid + 256];
  #pragma unroll
  for (int off = 1; off < 64; off <<= 1) s += __shfl_xor(s, off, 64);
  if ((tid & 63) == 0) rb[tid >> 6] = s;
  __syncthreads();
  if (tid == 0) out[0] = rb[0] + rb[1] + rb[2] + rb[3];
}

extern "C" void kernel_launch(void* const* d_in, const int* in_sizes, int n_in,
                              void* d_out, int out_size, void* d_ws,
                              size_t ws_size, hipStream_t stream) {
  const float* t = (const float*)d_in[0];
  const float* v = (const float*)d_in[1];
  const int* sidx = (const int*)d_in[2];
  float* out = (float*)d_out;
  float* slots = (float*)d_ws;  // 512 floats
  unsigned short* tn = (unsigned short*)((char*)d_ws + 4096);  // 4 MB
  unsigned short* vn = tn + (size_t)BDIM * DDIM;               // 4 MB

  norm_convert_kernel<<<4096, 256, 0, stream>>>(t, v, tn, vn, slots);
  loss_kernel<<<1024, 512, 0, stream>>>(tn, vn, slots);
  corr_kernel<<<2048, 256, 0, stream>>>(tn, vn, sidx, slots);
  reduce_kernel<<<1, 256, 0, stream>>>(slots, out);
}